// Round 21
// baseline (186.402 us; speedup 1.0000x reference)
//
#include <hip/hip_runtime.h>

#define B_    32
#define N_    256
#define H_    6
#define HD_   32
#define C_    192
#define C4_   768
#define TKIN  64
#define TKOUT 32

// ---------------------------------------------------------------------------
// Kernel A: one wave per (b,h,i) row; lane t owns sparse key slot t.
// f32 chain = R3 canonical (bit-exact: defines output values + tie classes).
// f64 ORDER KEY: okey = exp(acc64) * pv -- order-isomorphic to R20's a64
//   (a64 = ((e64/S)*pv + eps)/(D + eps) with row-shared S,D,eps: strictly
//   monotone in e64*pv in real math; f64 rounding noise ~2^-52 is far below
//   every decisive pair gap >= ~2^-30; duplicate-idx ties have identical e64
//   so both keys reduce to pv-order -- identical decisions to R20-PASS).
// No f64 max-subtract needed: |acc64| <= ~140 << 709 (exp f64 safe).
// Descending rank comparator (validated R20):
//   a32 bit-tie  -> ASCENDING okey ; a32 distinct -> DESCENDING okey.
// ---------------------------------------------------------------------------
__global__ __launch_bounds__(256) void attn_topk_kernel(
    const float* __restrict__ qkvp,
    const float* __restrict__ pfa_values,
    const int*   __restrict__ pfa_index,
    const int*   __restrict__ rpi,
    const float* __restrict__ rpb_table,
    float* __restrict__ x_pre,
    float* __restrict__ out_topv,
    float* __restrict__ out_nidx)
{
    const int lane  = threadIdx.x & 63;
    const int wslot = threadIdx.x >> 6;
    const int row   = (blockIdx.x << 2) + wslot;
    const int b   = row / (H_ * N_);
    const int rem = row - b * (H_ * N_);
    const int h   = rem / N_;
    const int i   = rem - h * N_;

    const int row_off = row * TKIN;
    const int idx  = pfa_index[row_off + lane];
    const float pv = pfa_values[row_off + lane];

    __shared__ float  s_e[4][64];
    __shared__ float  s_w[4][64];
    __shared__ float  s_k32[4][64];
    __shared__ double s_k64[4][64];    // okey
    __shared__ float  s_a[4][TKOUT];
    __shared__ int    s_i[4][TKOUT];

    const float* qp = qkvp + (size_t)(b * N_ + i) * C4_ + h * HD_;
    const float* kp = qkvp + (size_t)(b * N_ + idx) * C4_ + C_ + h * HD_;
    const float bias = rpb_table[rpi[i * N_ + idx] * H_ + h];

    // ---- f32 chain: sequential no-FMA dot (bit-exact, defines values) ----
    float acc;
    {
        #pragma clang fp contract(off)
        const float SC = 0.17677669529663687f;
        acc = 0.f;
        for (int d = 0; d < HD_; ++d) {
            const float qd   = qp[d] * SC;
            const float prod = qd * kp[d];
            acc = acc + prod;
        }
        acc = acc + bias;
    }
    // ---- f64 side chain: dot only (order key) ----
    double acc64;
    {
        const double SCD = 0.17677669529663687;
        acc64 = 0.0;
        for (int d = 0; d < HD_; ++d)
            acc64 += ((double)qp[d] * SCD) * (double)kp[d];
        acc64 += (double)bias;
    }
    const double okey = exp(acc64) * (double)pv;

    // ---- f32 row max (exact) ----
    float m = acc;
    #pragma unroll
    for (int s = 32; s; s >>= 1) m = fmaxf(m, __shfl_xor(m, s));

    // ---- e = exp(acc - m), correctly-rounded f32 via double ----
    float e;
    {
        #pragma clang fp contract(off)
        const float t = acc - m;
        e = (float)exp((double)t);
    }
    s_e[wslot][lane] = e;
    __syncthreads();

    // ---- ssum: numpy pairwise-8 ----
    float ssum;
    {
        #pragma clang fp contract(off)
        float r[8];
        #pragma unroll
        for (int j = 0; j < 8; ++j) r[j] = s_e[wslot][j];
        #pragma unroll
        for (int i8 = 8; i8 < 64; i8 += 8)
            #pragma unroll
            for (int j = 0; j < 8; ++j) r[j] = r[j] + s_e[wslot][i8 + j];
        ssum = ((r[0] + r[1]) + (r[2] + r[3])) + ((r[4] + r[5]) + (r[6] + r[7]));
    }

    // ---- w = (e/ssum)*pv ----
    float w;
    {
        #pragma clang fp contract(off)
        const float s32 = e / ssum;
        w = s32 * pv;
    }
    s_w[wslot][lane] = w;
    __syncthreads();

    // ---- denom: pairwise-8 ----
    float denom;
    {
        #pragma clang fp contract(off)
        float r[8];
        #pragma unroll
        for (int j = 0; j < 8; ++j) r[j] = s_w[wslot][j];
        #pragma unroll
        for (int i8 = 8; i8 < 64; i8 += 8)
            #pragma unroll
            for (int j = 0; j < 8; ++j) r[j] = r[j] + s_w[wslot][i8 + j];
        denom = ((r[0] + r[1]) + (r[2] + r[3])) + ((r[4] + r[5]) + (r[6] + r[7]));
    }

    // ---- a32 = (w + EPS)/(denom + EPS) ----
    float a32;
    {
        #pragma clang fp contract(off)
        a32 = (w + 1e-20f) / (denom + 1e-20f);
    }

    s_k32[wslot][lane] = a32;
    s_k64[wslot][lane] = okey;
    __syncthreads();

    // ---- rank: bit-tie -> ascending okey; distinct -> descending okey ----
    int rank = 0;
    #pragma unroll
    for (int j = 0; j < 64; ++j) {
        const float  kj32 = s_k32[wslot][j];
        const double kj64 = s_k64[wslot][j];
        bool before;
        if (kj32 == a32) {
            before = (kj64 < okey) || (kj64 == okey && j < lane);
        } else {
            before = (kj64 > okey) ||
                     (kj64 == okey && (kj32 > a32 || (kj32 == a32 && j < lane)));
        }
        rank += before;
    }

    if (rank < TKOUT) {
        const size_t obase = (size_t)row * TKOUT + rank;
        out_topv[obase] = a32;
        out_nidx[obase] = (float)idx;
        s_a[wslot][rank] = a32;
        s_i[wslot][rank] = idx;
    }
    __syncthreads();

    // ---- PV ----
    const int d    = lane & 31;
    const int half = lane >> 5;
    float xd = 0.f;
    #pragma unroll
    for (int s16 = 0; s16 < 16; ++s16) {
        const int sI = half * 16 + s16;
        const float av = s_a[wslot][sI];
        const int   vi = s_i[wslot][sI];
        xd += av * qkvp[(size_t)(b * N_ + vi) * C4_ + 2 * C_ + h * HD_ + d];
    }
    xd += __shfl_xor(xd, 32);
    if (half == 0) {
        const float lepe = qkvp[(size_t)(b * N_ + i) * C4_ + 3 * C_ + h * HD_ + d];
        x_pre[(size_t)(b * N_ + i) * C_ + h * HD_ + d] = xd + lepe;
    }
}

// ---------------------------------------------------------------------------
#define TB_ 8
__global__ __launch_bounds__(192) void proj_kernel(
    const float* __restrict__ x_pre,
    const float* __restrict__ w,
    const float* __restrict__ bias,
    float* __restrict__ out)
{
    __shared__ float xs[TB_ * C_];
    const int o    = threadIdx.x;
    const int tok0 = blockIdx.x * TB_;

    #pragma unroll
    for (int r = 0; r < TB_; ++r)
        xs[r * C_ + o] = x_pre[(size_t)(tok0 + r) * C_ + o];
    __syncthreads();

    float accv[TB_];
    #pragma unroll
    for (int t = 0; t < TB_; ++t) accv[t] = 0.f;

    const float* wrow = w + (size_t)o * C_;
    for (int c = 0; c < C_; c += 4) {
        const float4 wv = *(const float4*)(wrow + c);
        #pragma unroll
        for (int t = 0; t < TB_; ++t) {
            const float4 xv = *(const float4*)(&xs[t * C_ + c]);
            accv[t] += xv.x * wv.x + xv.y * wv.y + xv.z * wv.z + xv.w * wv.w;
        }
    }
    const float bo = bias[o];
    #pragma unroll
    for (int t = 0; t < TB_; ++t)
        out[(size_t)(tok0 + t) * C_ + o] = accv[t] + bo;
}

// ---------------------------------------------------------------------------
extern "C" void kernel_launch(void* const* d_in, const int* in_sizes, int n_in,
                              void* d_out, int out_size, void* d_ws, size_t ws_size,
                              hipStream_t stream) {
    const float* qkvp       = (const float*)d_in[0];
    const float* pfa_values = (const float*)d_in[1];
    const int*   pfa_index  = (const int*)d_in[2];
    const int*   rpi        = (const int*)d_in[3];
    const float* rpb_table  = (const float*)d_in[4];
    const float* proj_w     = (const float*)d_in[5];
    const float* proj_b     = (const float*)d_in[6];

    float* out = (float*)d_out;
    float* out_x    = out;
    float* out_topv = out + (size_t)B_ * N_ * C_;
    float* out_nidx = out_topv + (size_t)B_ * H_ * N_ * TKOUT;

    float* x_pre = (float*)d_ws;

    const int rows = B_ * H_ * N_;
    attn_topk_kernel<<<rows / 4, 256, 0, stream>>>(
        qkvp, pfa_values, pfa_index, rpi, rpb_table, x_pre, out_topv, out_nidx);

    const int ntok = B_ * N_;
    proj_kernel<<<ntok / TB_, 192, 0, stream>>>(x_pre, proj_w, proj_b, out_x);
}

// Round 22
// 161.399 us; speedup vs baseline: 1.1549x; 1.1549x over previous
//
#include <hip/hip_runtime.h>

#define B_    32
#define N_    256
#define H_    6
#define HD_   32
#define C_    192
#define C4_   768
#define TKIN  64
#define TKOUT 32

// ---------------------------------------------------------------------------
// Kernel A: one wave per (b,h,i) row; lane t owns sparse key slot t.
// f32 chain bit-identical to R20/R21-PASS. okey = exp(acc64)*pv (R21-validated
// order key). NO __syncthreads: all LDS arrays are per-wave slices (within-
// wave RAW ordered by lgkmcnt). Pairwise-8 sums via shuffles, bit-exact:
//   r_j = x[j]+x[8+j]+...+x[56+j] (left-assoc chain = 7x shfl_down(8))
//   ssum = ((r0+r1)+(r2+r3))+((r4+r5)+(r6+r7)) = shfl_xor 1,2,4 butterfly.
// Comparator (validated R20/R21): a32 bit-tie -> ASC okey; distinct -> DESC.
// ---------------------------------------------------------------------------
__global__ __launch_bounds__(256) void attn_topk_kernel(
    const float* __restrict__ qkvp,
    const float* __restrict__ pfa_values,
    const int*   __restrict__ pfa_index,
    const int*   __restrict__ rpi,
    const float* __restrict__ rpb_table,
    float* __restrict__ x_pre,
    float* __restrict__ out_topv,
    float* __restrict__ out_nidx)
{
    const int lane  = threadIdx.x & 63;
    const int wslot = threadIdx.x >> 6;
    const int row   = (blockIdx.x << 2) + wslot;
    const int b   = row / (H_ * N_);
    const int rem = row - b * (H_ * N_);
    const int h   = rem / N_;
    const int i   = rem - h * N_;

    const int row_off = row * TKIN;
    const int idx  = pfa_index[row_off + lane];
    const float pv = pfa_values[row_off + lane];

    __shared__ float  s_k32[4][64];
    __shared__ double s_k64[4][64];
    __shared__ float  s_a[4][TKOUT];
    __shared__ int    s_i[4][TKOUT];

    const float* qp = qkvp + (size_t)(b * N_ + i) * C4_ + h * HD_;
    const float* kp = qkvp + (size_t)(b * N_ + idx) * C4_ + C_ + h * HD_;
    const float bias = rpb_table[rpi[i * N_ + idx] * H_ + h];

    // ---- f32 chain: sequential no-FMA dot (bit-exact) ----
    float acc;
    {
        #pragma clang fp contract(off)
        const float SC = 0.17677669529663687f;
        acc = 0.f;
        for (int d = 0; d < HD_; ++d) {
            const float qd   = qp[d] * SC;
            const float prod = qd * kp[d];
            acc = acc + prod;
        }
        acc = acc + bias;
    }
    // ---- f64 order key ----
    double acc64;
    {
        const double SCD = 0.17677669529663687;
        acc64 = 0.0;
        for (int d = 0; d < HD_; ++d)
            acc64 += ((double)qp[d] * SCD) * (double)kp[d];
        acc64 += (double)bias;
    }
    const double okey = exp(acc64) * (double)pv;

    // ---- f32 row max (exact, order-independent) ----
    float m = acc;
    #pragma unroll
    for (int s = 32; s; s >>= 1) m = fmaxf(m, __shfl_xor(m, s));

    // ---- e = exp(acc - m), correctly-rounded f32 via double ----
    float e;
    {
        #pragma clang fp contract(off)
        const float t = acc - m;
        e = (float)exp((double)t);
    }

    // ---- ssum: numpy pairwise-8 via shuffles (bit-exact order) ----
    float ssum;
    {
        #pragma clang fp contract(off)
        float y = e, r = e;
        #pragma unroll
        for (int k = 1; k < 8; ++k) { y = __shfl_down(y, 8); r = r + y; }
        const float t1 = r  + __shfl_xor(r, 1);
        const float t2 = t1 + __shfl_xor(t1, 2);
        const float t3 = t2 + __shfl_xor(t2, 4);
        ssum = __shfl(t3, 0);
    }

    // ---- w = (e/ssum)*pv ----
    float w;
    {
        #pragma clang fp contract(off)
        const float s32 = e / ssum;
        w = s32 * pv;
    }

    // ---- denom: same shuffle pairwise-8 over w ----
    float denom;
    {
        #pragma clang fp contract(off)
        float y = w, r = w;
        #pragma unroll
        for (int k = 1; k < 8; ++k) { y = __shfl_down(y, 8); r = r + y; }
        const float t1 = r  + __shfl_xor(r, 1);
        const float t2 = t1 + __shfl_xor(t1, 2);
        const float t3 = t2 + __shfl_xor(t2, 4);
        denom = __shfl(t3, 0);
    }

    // ---- a32 = (w + EPS)/(denom + EPS) ----
    float a32;
    {
        #pragma clang fp contract(off)
        a32 = (w + 1e-20f) / (denom + 1e-20f);
    }

    s_k32[wslot][lane] = a32;
    s_k64[wslot][lane] = okey;
    // no barrier: per-wave LDS slice, lgkmcnt orders RAW within the wave

    // ---- rank: bit-tie -> ascending okey; distinct -> descending okey ----
    int rank = 0;
    #pragma unroll
    for (int j = 0; j < 64; ++j) {
        const float  kj32 = s_k32[wslot][j];
        const double kj64 = s_k64[wslot][j];
        bool before;
        if (kj32 == a32) {
            before = (kj64 < okey) || (kj64 == okey && j < lane);
        } else {
            before = (kj64 > okey) ||
                     (kj64 == okey && (kj32 > a32 || (kj32 == a32 && j < lane)));
        }
        rank += before;
    }

    if (rank < TKOUT) {
        const size_t obase = (size_t)row * TKOUT + rank;
        out_topv[obase] = a32;
        out_nidx[obase] = (float)idx;
        s_a[wslot][rank] = a32;
        s_i[wslot][rank] = idx;
    }

    // ---- PV (reads own wave's s_a/s_i; ordered by lgkmcnt) ----
    const int d    = lane & 31;
    const int half = lane >> 5;
    float xd = 0.f;
    #pragma unroll
    for (int s16 = 0; s16 < 16; ++s16) {
        const int sI = half * 16 + s16;
        const float av = s_a[wslot][sI];
        const int   vi = s_i[wslot][sI];
        xd += av * qkvp[(size_t)(b * N_ + vi) * C4_ + 2 * C_ + h * HD_ + d];
    }
    xd += __shfl_xor(xd, 32);
    if (half == 0) {
        const float lepe = qkvp[(size_t)(b * N_ + i) * C4_ + 3 * C_ + h * HD_ + d];
        x_pre[(size_t)(b * N_ + i) * C_ + h * HD_ + d] = xd + lepe;
    }
}

// ---------------------------------------------------------------------------
#define TB_ 8
__global__ __launch_bounds__(192) void proj_kernel(
    const float* __restrict__ x_pre,
    const float* __restrict__ w,
    const float* __restrict__ bias,
    float* __restrict__ out)
{
    __shared__ float xs[TB_ * C_];
    const int o    = threadIdx.x;
    const int tok0 = blockIdx.x * TB_;

    #pragma unroll
    for (int r = 0; r < TB_; ++r)
        xs[r * C_ + o] = x_pre[(size_t)(tok0 + r) * C_ + o];
    __syncthreads();

    float accv[TB_];
    #pragma unroll
    for (int t = 0; t < TB_; ++t) accv[t] = 0.f;

    const float* wrow = w + (size_t)o * C_;
    for (int c = 0; c < C_; c += 4) {
        const float4 wv = *(const float4*)(wrow + c);
        #pragma unroll
        for (int t = 0; t < TB_; ++t) {
            const float4 xv = *(const float4*)(&xs[t * C_ + c]);
            accv[t] += xv.x * wv.x + xv.y * wv.y + xv.z * wv.z + xv.w * wv.w;
        }
    }
    const float bo = bias[o];
    #pragma unroll
    for (int t = 0; t < TB_; ++t)
        out[(size_t)(tok0 + t) * C_ + o] = accv[t] + bo;
}

// ---------------------------------------------------------------------------
extern "C" void kernel_launch(void* const* d_in, const int* in_sizes, int n_in,
                              void* d_out, int out_size, void* d_ws, size_t ws_size,
                              hipStream_t stream) {
    const float* qkvp       = (const float*)d_in[0];
    const float* pfa_values = (const float*)d_in[1];
    const int*   pfa_index  = (const int*)d_in[2];
    const int*   rpi        = (const int*)d_in[3];
    const float* rpb_table  = (const float*)d_in[4];
    const float* proj_w     = (const float*)d_in[5];
    const float* proj_b     = (const float*)d_in[6];

    float* out = (float*)d_out;
    float* out_x    = out;
    float* out_topv = out + (size_t)B_ * N_ * C_;
    float* out_nidx = out_topv + (size_t)B_ * H_ * N_ * TKOUT;

    float* x_pre = (float*)d_ws;

    const int rows = B_ * H_ * N_;
    attn_topk_kernel<<<rows / 4, 256, 0, stream>>>(
        qkvp, pfa_values, pfa_index, rpi, rpb_table, x_pre, out_topv, out_nidx);

    const int ntok = B_ * N_;
    proj_kernel<<<ntok / TB_, 192, 0, stream>>>(x_pre, proj_w, proj_b, out_x);
}